// Round 7
// baseline (23.310 us; speedup 1.0000x reference)
//
#include <hip/hip_runtime.h>

#define FS    5
#define NTAP  25
#define Bc    8
#define Cc    32
#define CG    8                     // channels per block
#define Hc    128
#define Wc    128
#define HW    (Hc * Wc)

#define TH      8
#define TW      64
#define HALO_H  12                   // TH + 4
#define HALO_W  72                   // [w0-4, w0+68): float4-aligned left edge
#define PLANE   (HALO_H * HALO_W)    // 864 floats
#define F4_PER_PLANE (PLANE / 4)     // 216
#define F4_TOTAL     (CG * F4_PER_PLANE)  // 1728
#define LDS_BYTES    (CG * PLANE * 4)     // 27648 B -> 4+ blocks/CU

// zero-initialized device global: OOB lanes' DMA source (16B aligned)
__device__ __attribute__((aligned(16))) float ZERO4[4];

__device__ __forceinline__ void gload_lds16(const float* g, float* lds) {
    __builtin_amdgcn_global_load_lds(
        (const __attribute__((address_space(1))) void*)g,
        (__attribute__((address_space(3))) void*)lds, 16, 0, 0);
}

// One block = one 8x64 tile of one image, ONE 8-channel group.
// Stage own 8 halo planes via global_load_lds DMA (27.6 KB LDS -> 4 blocks/CU,
// 16 waves/CU: stage of one block overlaps compute of others).
// Gen: own 8 ch from LDS + other 24 ch center pixels from global (L2-resident,
// sibling ch-group blocks on the same XCD stage those lines), ping-pong batches.
// Apply: 5x5 over own 8 ch from LDS, float2. One barrier.
__global__ __launch_bounds__(256, 4) void ppdfn_fused(
    const float* __restrict__ x, const float* __restrict__ wg,
    const float* __restrict__ bg, float* __restrict__ out)
{
    extern __shared__ float xs[];     // [CG][HALO_H][HALO_W]

    const int tid = threadIdx.x;
    const int bid = blockIdx.x;
    // id = ht + 16*wt + 32*chg + 128*b ; delta(chg)=32 == 0 mod 8 -> the 4
    // ch-group blocks of one tile land on the same XCD (L2 locality for
    // the gen-other reads).
    const int ht  = bid & 15;
    const int wt  = (bid >> 4) & 1;
    const int chg = (bid >> 5) & 3;
    const int b   = bid >> 7;
    const int h0  = ht * TH;
    const int w0  = wt * TW;
    const int c0  = chg * CG;

    const float* xb = x  + (size_t)b * Cc * HW;
    const float* xo = xb + (size_t)c0 * HW;

    // ---- phase 1: DMA-stage own 8 halo planes (<=7 dwordx4 per thread) ----
#pragma unroll
    for (int k = 0; k < 7; ++k) {
        const int f = k * 256 + tid;             // flat float4 index
        if (f < F4_TOTAL) {                      // k==6: wave-uniform guard
            const int c  = f / F4_PER_PLANE;     // /216 (magic mul)
            const int rm = f - c * F4_PER_PLANE;
            const int r  = rm / 18;
            const int c4 = rm - r * 18;
            const int gh = h0 - 2 + r;
            const int gw = w0 - 4 + 4 * c4;
            const bool v = ((unsigned)gh < (unsigned)Hc) &&
                           ((unsigned)gw <= (unsigned)(Wc - 4));
            const float* src = v ? (xo + (size_t)c * HW + gh * Wc + gw) : ZERO4;
            // LDS dest: wave-uniform base, lane offset implicit (x16B)
            gload_lds16(src, xs + (size_t)k * 1024 + (size_t)(tid >> 6) * 256);
        }
    }

    // ---- pre-barrier: issue gen-other batch A (first sibling group) ----
    const int ty = tid >> 5;          // 0..7
    const int tx = tid & 31;          // 0..31
    const int w2 = tx * 2;
    const int centerOff = (h0 + ty) * Wc + (w0 + w2);

    const int og0 = ((chg + 1) & 3) * CG;
    const int og1 = ((chg + 2) & 3) * CG;
    const int og2 = ((chg + 3) & 3) * CG;

    float2 xoA[CG], xoB[CG];
    {
        const float* p = xb + (size_t)og0 * HW + centerOff;
#pragma unroll
        for (int u = 0; u < CG; ++u)
            xoA[u] = *reinterpret_cast<const float2*>(p + (size_t)u * HW);
    }

    float fx[NTAP], fy[NTAP];
#pragma unroll
    for (int t = 0; t < NTAP; ++t) { const float bv = bg[t]; fx[t] = bv; fy[t] = bv; }

    __syncthreads();

    // ---- phase 2: filter generation (2 px per thread, all 32 channels) ----
    // own 8 channels from LDS
#pragma unroll
    for (int c = 0; c < CG; ++c) {
        const float2 xv = *reinterpret_cast<const float2*>(
            xs + c * PLANE + (ty + 2) * HALO_W + (w2 + 4));
        const float* wrow = wg + (c0 + c);
#pragma unroll
        for (int t = 0; t < NTAP; ++t) {
            const float wv = wrow[t * Cc];       // wave-uniform -> s_load
            fx[t] = fmaf(wv, xv.x, fx[t]);
            fy[t] = fmaf(wv, xv.y, fy[t]);
        }
    }
    // issue B = og1, consume A (og0)
    {
        const float* p = xb + (size_t)og1 * HW + centerOff;
#pragma unroll
        for (int u = 0; u < CG; ++u)
            xoB[u] = *reinterpret_cast<const float2*>(p + (size_t)u * HW);
    }
#pragma unroll
    for (int u = 0; u < CG; ++u) {
        const float2 xv = xoA[u];
        const float* wrow = wg + (og0 + u);
#pragma unroll
        for (int t = 0; t < NTAP; ++t) {
            const float wv = wrow[t * Cc];
            fx[t] = fmaf(wv, xv.x, fx[t]);
            fy[t] = fmaf(wv, xv.y, fy[t]);
        }
    }
    // issue A = og2, consume B (og1)
    {
        const float* p = xb + (size_t)og2 * HW + centerOff;
#pragma unroll
        for (int u = 0; u < CG; ++u)
            xoA[u] = *reinterpret_cast<const float2*>(p + (size_t)u * HW);
    }
#pragma unroll
    for (int u = 0; u < CG; ++u) {
        const float2 xv = xoB[u];
        const float* wrow = wg + (og1 + u);
#pragma unroll
        for (int t = 0; t < NTAP; ++t) {
            const float wv = wrow[t * Cc];
            fx[t] = fmaf(wv, xv.x, fx[t]);
            fy[t] = fmaf(wv, xv.y, fy[t]);
        }
    }
    // consume A (og2)
#pragma unroll
    for (int u = 0; u < CG; ++u) {
        const float2 xv = xoA[u];
        const float* wrow = wg + (og2 + u);
#pragma unroll
        for (int t = 0; t < NTAP; ++t) {
            const float wv = wrow[t * Cc];
            fx[t] = fmaf(wv, xv.x, fx[t]);
            fy[t] = fmaf(wv, xv.y, fy[t]);
        }
    }

    // ---- phase 3: apply 5x5 over own 8 channels ----
    float* ob = out + ((size_t)b * Cc + c0) * HW + centerOff;
#pragma unroll
    for (int c = 0; c < CG; ++c) {
        const float* p = xs + c * PLANE + ty * HALO_W + (w2 + 2);
        float ax = 0.f, ay = 0.f;
#pragma unroll
        for (int di = 0; di < FS; ++di) {
            const float* row = p + di * HALO_W;
            const float2 s01 = *reinterpret_cast<const float2*>(row);
            const float2 s23 = *reinterpret_cast<const float2*>(row + 2);
            const float2 s45 = *reinterpret_cast<const float2*>(row + 4);
            const float s0 = s01.x, s1 = s01.y, s2 = s23.x,
                        s3 = s23.y, s4 = s45.x, s5 = s45.y;
            ax = fmaf(fx[di * FS + 0], s0, ax);  ay = fmaf(fy[di * FS + 0], s1, ay);
            ax = fmaf(fx[di * FS + 1], s1, ax);  ay = fmaf(fy[di * FS + 1], s2, ay);
            ax = fmaf(fx[di * FS + 2], s2, ax);  ay = fmaf(fy[di * FS + 2], s3, ay);
            ax = fmaf(fx[di * FS + 3], s3, ax);  ay = fmaf(fy[di * FS + 3], s4, ay);
            ax = fmaf(fx[di * FS + 4], s4, ax);  ay = fmaf(fy[di * FS + 4], s5, ay);
        }
        *reinterpret_cast<float2*>(ob + (size_t)c * HW) = make_float2(ax, ay);
    }
}

extern "C" void kernel_launch(void* const* d_in, const int* in_sizes, int n_in,
                              void* d_out, int out_size, void* d_ws, size_t ws_size,
                              hipStream_t stream) {
    const float* x  = (const float*)d_in[0];
    const float* wg = (const float*)d_in[1];
    const float* bg = (const float*)d_in[2];
    float* out = (float*)d_out;

    ppdfn_fused<<<dim3(1024), 256, LDS_BYTES, stream>>>(x, wg, bg, out);
}